// Round 6
// baseline (1076.731 us; speedup 1.0000x reference)
//
#include <hip/hip_runtime.h>
#include <hip/hip_bf16.h>

#define H64 64

typedef __bf16 bf16_t;
typedef __bf16 bf16x8 __attribute__((ext_vector_type(8)));
typedef float f32x4 __attribute__((ext_vector_type(4)));

// ---------- helpers ----------
__device__ __forceinline__ float wload(const void* p, long i, bool f32) {
    return f32 ? ((const float*)p)[i]
               : __bfloat162float(((const __hip_bfloat16*)p)[i]);
}
__device__ __forceinline__ float blo(unsigned v) { return __uint_as_float(v << 16); }
__device__ __forceinline__ float bhi(unsigned v) { return __uint_as_float(v & 0xffff0000u); }

// ---------- runtime format detection ----------
// flags[0] != 0 -> edge indices int32 (odd words nonzero); ==0 -> int64
// flags[1] > 64 -> x tensors f32; else bf16.  flags[2] > 64 -> weights f32.
__global__ void detect_k(const unsigned int* __restrict__ eiw, int nwords,
                         const unsigned short* __restrict__ xw,
                         const unsigned short* __restrict__ ww,
                         unsigned int* __restrict__ flags) {
    int t = threadIdx.x;
    unsigned int acc = 0;
    for (int i = 1 + 2 * t; i < nwords; i += 512) acc |= eiw[i];
    if (acc) atomicOr(&flags[0], acc);
    unsigned int cx = 0, cw = 0;
    for (int i = t; i < 8192; i += 256) {
        unsigned short w = xw[i];
        unsigned int e = (w >> 7) & 0xFF;
        if ((w & 0x7FFF) && (e == 0xFF || e < 0x40)) cx++;
        w = ww[i];
        e = (w >> 7) & 0xFF;
        if ((w & 0x7FFF) && (e == 0xFF || e < 0x40)) cw++;
    }
    if (cx) atomicAdd(&flags[1], cx);
    if (cw) atomicAdd(&flags[2], cw);
}

// ---------- convert harness x input -> bf16 ws storage ----------
__global__ void conv_in(const void* __restrict__ src, __hip_bfloat16* __restrict__ dst,
                        long n, const unsigned int* __restrict__ flags) {
    bool xf32 = flags[1] > 64;
    long i = (long)blockIdx.x * blockDim.x + threadIdx.x;
    long stride = (long)gridDim.x * blockDim.x;
    for (; i < n; i += stride) {
        float v = xf32 ? ((const float*)src)[i]
                       : __bfloat162float(((const __hip_bfloat16*)src)[i]);
        dst[i] = __float2bfloat16(v);
    }
}

// ---------- weight prep: bf16, transposed WT[n][k]; Wr pre-summed per (l,dt) ----------
// blockIdx.x = l*13 + p.  p<9: WT of Wl[l,p].  p in 9..12: dt=p-9, WT of sum(Wr) + blsum.
__global__ void prep_w(const void* __restrict__ Wl, const void* __restrict__ Wr,
                       const void* __restrict__ bl, const unsigned int* __restrict__ flags,
                       bf16_t* __restrict__ wt, float* __restrict__ blsum) {
    const int rel_dt[9] = {0, 1, 2, 1, 2, 2, 3, 3, 3};
    bool wf32 = flags[2] > 64;
    int l = blockIdx.x / 13, p = blockIdx.x % 13;
    bf16_t* dst = wt + (long)blockIdx.x * 4096;
    for (int i = threadIdx.x; i < 4096; i += 256) {
        int n = i >> 6, k = i & 63;
        float v;
        if (p < 9) {
            v = wload(Wl, (long)(l * 9 + p) * 4096 + k * 64 + n, wf32);
        } else {
            int dt = p - 9;
            v = 0.f;
            for (int r = 0; r < 9; ++r)
                if (rel_dt[r] == dt) v += wload(Wr, (long)(l * 9 + r) * 4096 + k * 64 + n, wf32);
        }
        __hip_bfloat16 h = __float2bfloat16(v);
        dst[i] = *(bf16_t*)&h;
    }
    if (p >= 9 && threadIdx.x < 64) {
        int dt = p - 9;
        float s = 0.f;
        for (int r = 0; r < 9; ++r)
            if (rel_dt[r] == dt) s += wload(bl, (long)(l * 9 + r) * 64 + threadIdx.x, wf32);
        blsum[(l * 4 + dt) * 64 + threadIdx.x] = s;
    }
}

// ---------- consolidated CSR build ----------
struct EdgeArgs {
    const int* ei[9];
    long eoff[10];
    int cntoff[9];
    int srcbase[9];
};

__global__ void count_all(EdgeArgs ea, const unsigned int* __restrict__ flags,
                          int* __restrict__ cnt) {
    long e = (long)blockIdx.x * 256 + threadIdx.x;
    if (e >= ea.eoff[9]) return;
    int r = 0;
    while (r < 8 && e >= ea.eoff[r + 1]) ++r;
    long el = e - ea.eoff[r];
    long E = ea.eoff[r + 1] - ea.eoff[r];
    bool is64 = (flags[0] == 0u);
    const int* ei = ea.ei[r];
    int dst = is64 ? ei[2 * E + 2 * el] : ei[E + el];
    atomicAdd(&cnt[ea.cntoff[r] + dst], 1);
}

__global__ void fill_all(EdgeArgs ea, const unsigned int* __restrict__ flags,
                         int* __restrict__ cursor, int* __restrict__ edge_src) {
    long e = (long)blockIdx.x * 256 + threadIdx.x;
    if (e >= ea.eoff[9]) return;
    int r = 0;
    while (r < 8 && e >= ea.eoff[r + 1]) ++r;
    long el = e - ea.eoff[r];
    long E = ea.eoff[r + 1] - ea.eoff[r];
    bool is64 = (flags[0] == 0u);
    const int* ei = ea.ei[r];
    int src, dst;
    if (is64) { src = ei[2 * el]; dst = ei[2 * E + 2 * el]; }
    else      { src = ei[el];     dst = ei[E + el]; }
    int pos = atomicAdd(&cursor[ea.cntoff[r] + dst], 1);
    edge_src[pos] = ea.srcbase[r] + src;
}

__global__ void scan_bsum(const int* __restrict__ cnt, int n, int* __restrict__ bsums) {
    __shared__ int red[256];
    int i = blockIdx.x * 256 + threadIdx.x;
    red[threadIdx.x] = (i < n) ? cnt[i] : 0;
    __syncthreads();
    for (int s = 128; s; s >>= 1) {
        if (threadIdx.x < s) red[threadIdx.x] += red[threadIdx.x + s];
        __syncthreads();
    }
    if (threadIdx.x == 0) bsums[blockIdx.x] = red[0];
}

__global__ void scan_excl_single(int* __restrict__ data, int n) {
    __shared__ int buf[1024];
    __shared__ int carry_s;
    if (threadIdx.x == 0) carry_s = 0;
    __syncthreads();
    for (int base = 0; base < n; base += 1024) {
        int i = base + threadIdx.x;
        int v = (i < n) ? data[i] : 0;
        buf[threadIdx.x] = v;
        __syncthreads();
        for (int off = 1; off < 1024; off <<= 1) {
            int tv = (threadIdx.x >= off) ? buf[threadIdx.x - off] : 0;
            __syncthreads();
            buf[threadIdx.x] += tv;
            __syncthreads();
        }
        int incl = buf[threadIdx.x];
        int carry = carry_s;
        if (i < n) data[i] = carry + incl - v;
        __syncthreads();
        if (threadIdx.x == 1023) carry_s = carry + buf[1023];
        __syncthreads();
    }
}

__global__ void scan_rowptr(const int* __restrict__ cnt, const int* __restrict__ bsums,
                            int n, int* __restrict__ row_ptr) {
    __shared__ int buf[256];
    int i = blockIdx.x * 256 + threadIdx.x;
    int v = (i < n) ? cnt[i] : 0;
    buf[threadIdx.x] = v;
    __syncthreads();
    for (int off = 1; off < 256; off <<= 1) {
        int tv = (threadIdx.x >= off) ? buf[threadIdx.x - off] : 0;
        __syncthreads();
        buf[threadIdx.x] += tv;
        __syncthreads();
    }
    int excl = buf[threadIdx.x] - v + bsums[blockIdx.x];
    if (i < n) row_ptr[i] = excl;
    if (i == n - 1) row_ptr[n] = excl + v;
}

// ---------- gather-mean: half-wave (32 lanes) per dst row, unroll 8 ----------
__global__ void gather_mean(const __hip_bfloat16* __restrict__ x,
                            const int* __restrict__ edge_src,
                            const int* __restrict__ row_ptr,
                            __hip_bfloat16* __restrict__ agg, int nrows) {
    int w = blockIdx.x * 8 + (threadIdx.x >> 5);
    int lane = threadIdx.x & 31;
    if (w >= nrows) return;
    int s = row_ptr[w], t = row_ptr[w + 1];
    const unsigned* xu = (const unsigned*)x;
    float a0 = 0.f, a1 = 0.f;
    int e = s;
    for (; e + 8 <= t; e += 8) {
        int i0 = edge_src[e],     i1 = edge_src[e + 1], i2 = edge_src[e + 2], i3 = edge_src[e + 3];
        int i4 = edge_src[e + 4], i5 = edge_src[e + 5], i6 = edge_src[e + 6], i7 = edge_src[e + 7];
        unsigned v0 = xu[(long)i0 * 32 + lane];
        unsigned v1 = xu[(long)i1 * 32 + lane];
        unsigned v2 = xu[(long)i2 * 32 + lane];
        unsigned v3 = xu[(long)i3 * 32 + lane];
        unsigned v4 = xu[(long)i4 * 32 + lane];
        unsigned v5 = xu[(long)i5 * 32 + lane];
        unsigned v6 = xu[(long)i6 * 32 + lane];
        unsigned v7 = xu[(long)i7 * 32 + lane];
        a0 += ((blo(v0) + blo(v1)) + (blo(v2) + blo(v3))) +
              ((blo(v4) + blo(v5)) + (blo(v6) + blo(v7)));
        a1 += ((bhi(v0) + bhi(v1)) + (bhi(v2) + bhi(v3))) +
              ((bhi(v4) + bhi(v5)) + (bhi(v6) + bhi(v7)));
    }
    for (; e + 2 <= t; e += 2) {
        unsigned v0 = xu[(long)edge_src[e] * 32 + lane];
        unsigned v1 = xu[(long)edge_src[e + 1] * 32 + lane];
        a0 += blo(v0) + blo(v1);
        a1 += bhi(v0) + bhi(v1);
    }
    for (; e < t; ++e) {
        unsigned v = xu[(long)edge_src[e] * 32 + lane];
        a0 += blo(v); a1 += bhi(v);
    }
    float inv = (t > s) ? 1.0f / (float)(t - s) : 0.f;
    __hip_bfloat162 o;
    o.x = __float2bfloat16(a0 * inv);
    o.y = __float2bfloat16(a1 * inv);
    ((__hip_bfloat162*)agg)[(long)w * 32 + lane] = o;
}

// ---------- layer update: register-resident weights, direct-global A, no LDS ----------
// x[d,:] = relu( sum_p agg_p[d,:] @ Wl_p + x[d,:] @ Wsum + blsum ),  in place.
struct UpdArgs {
    long aggOff[4][3];  // agg row offset per (dt, pass)
    int wtSlot[4][4];   // weight slot per (dt, pass); [3] = self
    long dstBase[4];    // global row base of dt
    int nDst[4];
    int Rdt[4];
    int blsumOff[4];
    int btBase[5];      // cumulative 64-row block-tiles per dt (natural order)
    int totalBT;
};

__global__ __launch_bounds__(256) void update_layer(
    __hip_bfloat16* __restrict__ x,
    const __hip_bfloat16* __restrict__ agg,
    const bf16_t* __restrict__ wt,
    const float* __restrict__ blsum,
    UpdArgs ua, int btPerBlk) {
    int wv = threadIdx.x >> 6;
    int lane = threadIdx.x & 63;
    int quad = lane >> 4, l16 = lane & 15;
    int bt0 = blockIdx.x * btPerBlk;
    int bt1 = bt0 + btPerBlk;
    if (bt1 > ua.totalBT) bt1 = ua.totalBT;
    int curdt = -1;
    bf16x8 B[4][4][2];   // [pass][nt][kc] — compile-time indexed only

    for (int bt = bt0; bt < bt1; ++bt) {
        int slot = 0;
        while (slot < 3 && bt >= ua.btBase[slot + 1]) ++slot;
        int dt = slot;
        int R = ua.Rdt[dt];
        if (dt != curdt) {
            curdt = dt;
            #pragma unroll
            for (int p = 0; p < 4; ++p) {
                if (p <= R) {
                    const bf16_t* wb = wt + (long)ua.wtSlot[dt][p == R ? 3 : p] * 4096;
                    #pragma unroll
                    for (int nt = 0; nt < 4; ++nt)
                        #pragma unroll
                        for (int kc = 0; kc < 2; ++kc)
                            B[p][nt][kc] = *(const bf16x8*)(wb + (nt * 16 + l16) * 64 + kc * 32 + quad * 8);
                }
            }
        }
        long d0 = (long)(bt - ua.btBase[slot]) * 64 + wv * 16;   // wave's 16-row tile
        f32x4 acc[4] = {};
        #pragma unroll
        for (int p = 0; p < 4; ++p) {
            if (p <= R) {
                const bf16_t* abase = (p == R)
                    ? (const bf16_t*)x + (ua.dstBase[dt] + d0) * 64
                    : (const bf16_t*)agg + (ua.aggOff[dt][p == R ? 0 : p] + d0) * 64;
                bf16x8 a0 = *(const bf16x8*)(abase + l16 * 64 + quad * 8);
                bf16x8 a1 = *(const bf16x8*)(abase + l16 * 64 + 32 + quad * 8);
                #pragma unroll
                for (int nt = 0; nt < 4; ++nt) {
                    acc[nt] = __builtin_amdgcn_mfma_f32_16x16x32_bf16(a0, B[p][nt][0], acc[nt], 0, 0, 0);
                    acc[nt] = __builtin_amdgcn_mfma_f32_16x16x32_bf16(a1, B[p][nt][1], acc[nt], 0, 0, 0);
                }
            }
        }
        const float* bs = blsum + ua.blsumOff[dt];
        int n_dst = ua.nDst[dt];
        #pragma unroll
        for (int nt = 0; nt < 4; ++nt) {
            int col = nt * 16 + l16;
            float bv = bs[col];
            #pragma unroll
            for (int reg = 0; reg < 4; ++reg) {
                long dd = d0 + quad * 4 + reg;
                if (dd < n_dst)
                    x[(ua.dstBase[dt] + dd) * 64 + col] =
                        __float2bfloat16(fmaxf(acc[nt][reg] + bv, 0.f));
            }
        }
    }
}

// ---------- head: softplus(x@projW+projb) @ outW + outb ----------
__global__ __launch_bounds__(256) void head_k(
    const __hip_bfloat16* __restrict__ xc,
    const void* __restrict__ projW, const void* __restrict__ projb,
    const void* __restrict__ outW, const void* __restrict__ outb,
    void* __restrict__ out, const unsigned int* __restrict__ flags, int n) {
    __shared__ float PW[64 * 64];
    __shared__ float PB[64], OW[64];
    __shared__ float ROW[4][64];
    bool wf32 = flags[2] > 64;
    bool of32 = flags[1] > 64;
    int t = threadIdx.x;
    for (int i = t; i < 4096; i += 256) PW[i] = wload(projW, i, wf32);
    if (t < 64) { PB[t] = wload(projb, t, wf32); OW[t] = wload(outW, t, wf32); }
    int wid = t >> 6, lane = t & 63;
    int d = blockIdx.x * 4 + wid;
    ROW[wid][lane] = (d < n) ? __bfloat162float(xc[(long)d * H64 + lane]) : 0.f;
    __syncthreads();
    if (d < n) {
        float s = PB[lane];
        #pragma unroll 8
        for (int k = 0; k < 64; ++k) s += ROW[wid][k] * PW[k * 64 + lane];
        float sp = fmaxf(s, 0.f) + log1pf(expf(-fabsf(s)));
        float c = sp * OW[lane];
        #pragma unroll
        for (int off = 32; off; off >>= 1) c += __shfl_down(c, off, 64);
        if (lane == 0) {
            float rv = c + wload(outb, 0, wf32);
            if (of32) ((float*)out)[d] = rv;
            else ((__hip_bfloat16*)out)[d] = __float2bfloat16(rv);
        }
    }
}

extern "C" void kernel_launch(void* const* d_in, const int* in_sizes, int n_in,
                              void* d_out, int out_size, void* d_ws, size_t ws_size,
                              hipStream_t stream) {
    static const int rel_st[9] = {0, 0, 0, 1, 1, 2, 0, 1, 2};
    static const int rel_dt[9] = {0, 1, 2, 1, 2, 2, 3, 3, 3};
    static const int relsOf[4][3] = {{0, -1, -1}, {1, 3, -1}, {2, 4, 5}, {6, 7, 8}};
    static const int Rof[4] = {1, 2, 3, 3};

    long rows[4], rowoff[4], total = 0;
    for (int t = 0; t < 4; ++t) { rows[t] = in_sizes[t] / H64; rowoff[t] = total; total += rows[t]; }
    long NX = total * H64;
    long Es[9], ET = 0;
    for (int r = 0; r < 9; ++r) { Es[r] = (long)in_sizes[11 + r] / 2; ET += Es[r]; }
    long cntoff[9], cntN = 0;
    for (int r = 0; r < 9; ++r) { cntoff[r] = cntN; cntN += rows[rel_dt[r]]; }
    long nb1 = (cntN + 255) / 256;

    unsigned int* flags = (unsigned int*)d_ws;
    char* wsbase = (char*)d_ws + 64;
    auto align16 = [](size_t v) { return (v + 15) & ~(size_t)15; };
    size_t off = 0;
    __hip_bfloat16* x = (__hip_bfloat16*)(wsbase + off);   off = align16(off + (size_t)NX * 2);
    __hip_bfloat16* agg = (__hip_bfloat16*)(wsbase + off); off = align16(off + (size_t)cntN * H64 * 2);
    int* cnt_i = (int*)(wsbase + off);                     off = align16(off + (size_t)cntN * 4);
    int* row_ptr = (int*)(wsbase + off);                   off = align16(off + (size_t)(cntN + 1) * 4);
    int* cursor = (int*)(wsbase + off);                    off = align16(off + (size_t)cntN * 4);
    int* edge_src = (int*)(wsbase + off);                  off = align16(off + (size_t)ET * 4);
    int* bsums = (int*)(wsbase + off);                     off = align16(off + (size_t)nb1 * 4);
    bf16_t* wt = (bf16_t*)(wsbase + off);                  off = align16(off + (size_t)39 * 4096 * 2);
    float* blsum = (float*)(wsbase + off);                 off = align16(off + (size_t)12 * 64 * 4);

    // format detection
    hipMemsetAsync(d_ws, 0, 64, stream);
    int nwords = 16384;
    if (in_sizes[11] < nwords) nwords = in_sizes[11];
    detect_k<<<1, 256, 0, stream>>>((const unsigned int*)d_in[11], nwords,
                                    (const unsigned short*)d_in[0],
                                    (const unsigned short*)d_in[4], flags);

    // x inputs -> bf16 ws
    for (int t = 0; t < 4; ++t) {
        long n = rows[t] * H64;
        int blocks = (int)((n + 255) / 256); if (blocks > 8192) blocks = 8192;
        conv_in<<<blocks, 256, 0, stream>>>(d_in[t], x + rowoff[t] * H64, n, flags);
    }

    // weight prep (transpose + pre-sum, bf16)
    prep_w<<<39, 256, 0, stream>>>(d_in[4], d_in[6], d_in[5], flags, wt, blsum);

    // CSR build (edge structure is layer-invariant)
    EdgeArgs ea;
    long ecum = 0;
    for (int r = 0; r < 9; ++r) {
        ea.ei[r] = (const int*)d_in[11 + r];
        ea.eoff[r] = ecum; ecum += Es[r];
        ea.cntoff[r] = (int)cntoff[r];
        ea.srcbase[r] = (int)rowoff[rel_st[r]];
    }
    ea.eoff[9] = ecum;

    hipMemsetAsync(cnt_i, 0, (size_t)cntN * 4, stream);
    count_all<<<(int)((ET + 255) / 256), 256, 0, stream>>>(ea, flags, cnt_i);
    scan_bsum<<<(int)nb1, 256, 0, stream>>>(cnt_i, (int)cntN, bsums);
    scan_excl_single<<<1, 1024, 0, stream>>>(bsums, (int)nb1);
    scan_rowptr<<<(int)nb1, 256, 0, stream>>>(cnt_i, bsums, (int)cntN, row_ptr);
    hipMemcpyAsync(cursor, row_ptr, (size_t)cntN * 4, hipMemcpyDeviceToDevice, stream);
    fill_all<<<(int)((ET + 255) / 256), 256, 0, stream>>>(ea, flags, cursor, edge_src);

    // update-layer argument block (layer-invariant parts)
    UpdArgs ua;
    int bb = 0;
    for (int dt = 0; dt < 4; ++dt) {
        ua.nDst[dt] = (int)rows[dt];
        ua.Rdt[dt] = Rof[dt];
        ua.dstBase[dt] = rowoff[dt];
        ua.btBase[dt] = bb;
        bb += (int)((rows[dt] + 63) / 64);
        for (int p = 0; p < 3; ++p) {
            int rr = (p < Rof[dt]) ? relsOf[dt][p] : relsOf[dt][0];
            ua.aggOff[dt][p] = cntoff[rr];
        }
    }
    ua.btBase[4] = bb;
    ua.totalBT = bb;
    int btPerBlk = (bb + 1023) / 1024;
    if (btPerBlk < 1) btPerBlk = 1;
    int updGrid = (bb + btPerBlk - 1) / btPerBlk;

    // layers: gather (x -> agg), then in-place MFMA update
    for (int l = 0; l < 3; ++l) {
        gather_mean<<<(int)((cntN + 7) / 8), 256, 0, stream>>>(
            x, edge_src, row_ptr, agg, (int)cntN);
        for (int dt = 0; dt < 4; ++dt) {
            ua.blsumOff[dt] = (l * 4 + dt) * 64;
            for (int p = 0; p < 3; ++p) {
                int rr = (p < Rof[dt]) ? relsOf[dt][p] : relsOf[dt][0];
                ua.wtSlot[dt][p] = l * 13 + rr;
            }
            ua.wtSlot[dt][3] = l * 13 + 9 + dt;
        }
        update_layer<<<updGrid, 256, 0, stream>>>(x, agg, wt, blsum, ua, btPerBlk);
    }

    head_k<<<(int)((rows[3] + 3) / 4), 256, 0, stream>>>(
        x + rowoff[3] * H64, d_in[7], d_in[8], d_in[9], d_in[10], d_out, flags, (int)rows[3]);
}

// Round 7
// 1019.166 us; speedup vs baseline: 1.0565x; 1.0565x over previous
//
#include <hip/hip_runtime.h>
#include <hip/hip_bf16.h>

#define H64 64

typedef __bf16 bf16_t;
typedef __bf16 bf16x8 __attribute__((ext_vector_type(8)));
typedef float f32x4 __attribute__((ext_vector_type(4)));

// ---------- helpers ----------
__device__ __forceinline__ float wload(const void* p, long i, bool f32) {
    return f32 ? ((const float*)p)[i]
               : __bfloat162float(((const __hip_bfloat16*)p)[i]);
}
__device__ __forceinline__ float blo(unsigned v) { return __uint_as_float(v << 16); }
__device__ __forceinline__ float bhi(unsigned v) { return __uint_as_float(v & 0xffff0000u); }

// ---------- runtime format detection ----------
// flags[0] != 0 -> edge indices int32 (odd words nonzero); ==0 -> int64
// flags[1] > 64 -> x tensors f32; else bf16.  flags[2] > 64 -> weights f32.
__global__ void detect_k(const unsigned int* __restrict__ eiw, int nwords,
                         const unsigned short* __restrict__ xw,
                         const unsigned short* __restrict__ ww,
                         unsigned int* __restrict__ flags) {
    int t = threadIdx.x;
    unsigned int acc = 0;
    for (int i = 1 + 2 * t; i < nwords; i += 512) acc |= eiw[i];
    if (acc) atomicOr(&flags[0], acc);
    unsigned int cx = 0, cw = 0;
    for (int i = t; i < 8192; i += 256) {
        unsigned short w = xw[i];
        unsigned int e = (w >> 7) & 0xFF;
        if ((w & 0x7FFF) && (e == 0xFF || e < 0x40)) cx++;
        w = ww[i];
        e = (w >> 7) & 0xFF;
        if ((w & 0x7FFF) && (e == 0xFF || e < 0x40)) cw++;
    }
    if (cx) atomicAdd(&flags[1], cx);
    if (cw) atomicAdd(&flags[2], cw);
}

// ---------- convert all x inputs -> bf16 ws storage (single dispatch) ----------
struct ConvArgs {
    const void* src[4];
    long elemoff[5];   // element offsets (rows*64) per type, cumulative
};
__global__ void conv_in_all(ConvArgs ca, __hip_bfloat16* __restrict__ dst,
                            const unsigned int* __restrict__ flags) {
    bool xf32 = flags[1] > 64;
    long n = ca.elemoff[4];
    long i = (long)blockIdx.x * blockDim.x + threadIdx.x;
    long stride = (long)gridDim.x * blockDim.x;
    for (; i < n; i += stride) {
        int t = (i >= ca.elemoff[2]) ? (i >= ca.elemoff[3] ? 3 : 2)
                                     : (i >= ca.elemoff[1] ? 1 : 0);
        long j = i - ca.elemoff[t];
        float v = xf32 ? ((const float*)ca.src[t])[j]
                       : __bfloat162float(((const __hip_bfloat16*)ca.src[t])[j]);
        dst[i] = __float2bfloat16(v);
    }
}

// ---------- weight prep: bf16, transposed WT[n][k]; Wr pre-summed per (l,dt) ----------
// blockIdx.x = l*13 + p.  p<9: WT of Wl[l,p].  p in 9..12: dt=p-9, WT of sum(Wr) + blsum.
__global__ void prep_w(const void* __restrict__ Wl, const void* __restrict__ Wr,
                       const void* __restrict__ bl, const unsigned int* __restrict__ flags,
                       bf16_t* __restrict__ wt, float* __restrict__ blsum) {
    const int rel_dt[9] = {0, 1, 2, 1, 2, 2, 3, 3, 3};
    bool wf32 = flags[2] > 64;
    int l = blockIdx.x / 13, p = blockIdx.x % 13;
    bf16_t* dst = wt + (long)blockIdx.x * 4096;
    for (int i = threadIdx.x; i < 4096; i += 256) {
        int n = i >> 6, k = i & 63;
        float v;
        if (p < 9) {
            v = wload(Wl, (long)(l * 9 + p) * 4096 + k * 64 + n, wf32);
        } else {
            int dt = p - 9;
            v = 0.f;
            for (int r = 0; r < 9; ++r)
                if (rel_dt[r] == dt) v += wload(Wr, (long)(l * 9 + r) * 4096 + k * 64 + n, wf32);
        }
        __hip_bfloat16 h = __float2bfloat16(v);
        dst[i] = *(bf16_t*)&h;
    }
    if (p >= 9 && threadIdx.x < 64) {
        int dt = p - 9;
        float s = 0.f;
        for (int r = 0; r < 9; ++r)
            if (rel_dt[r] == dt) s += wload(bl, (long)(l * 9 + r) * 64 + threadIdx.x, wf32);
        blsum[(l * 4 + dt) * 64 + threadIdx.x] = s;
    }
}

// ---------- consolidated CSR build ----------
struct EdgeArgs {
    const int* ei[9];
    long eoff[10];
    int cntoff[9];
    int srcbase[9];
};

// count + emit per-edge rank (coalesced)
__global__ void count_all(EdgeArgs ea, const unsigned int* __restrict__ flags,
                          int* __restrict__ cnt, int* __restrict__ rank) {
    long e = (long)blockIdx.x * 256 + threadIdx.x;
    if (e >= ea.eoff[9]) return;
    int r = 0;
    while (r < 8 && e >= ea.eoff[r + 1]) ++r;
    long el = e - ea.eoff[r];
    long E = ea.eoff[r + 1] - ea.eoff[r];
    bool is64 = (flags[0] == 0u);
    const int* ei = ea.ei[r];
    int dst = is64 ? ei[2 * E + 2 * el] : ei[E + el];
    rank[e] = atomicAdd(&cnt[ea.cntoff[r] + dst], 1);
}

// atomic-free fill: pos = row_ptr[dst] + rank[e]
__global__ void fill_all(EdgeArgs ea, const unsigned int* __restrict__ flags,
                         const int* __restrict__ row_ptr, const int* __restrict__ rank,
                         int* __restrict__ edge_src) {
    long e = (long)blockIdx.x * 256 + threadIdx.x;
    if (e >= ea.eoff[9]) return;
    int r = 0;
    while (r < 8 && e >= ea.eoff[r + 1]) ++r;
    long el = e - ea.eoff[r];
    long E = ea.eoff[r + 1] - ea.eoff[r];
    bool is64 = (flags[0] == 0u);
    const int* ei = ea.ei[r];
    int src, dst;
    if (is64) { src = ei[2 * el]; dst = ei[2 * E + 2 * el]; }
    else      { src = ei[el];     dst = ei[E + el]; }
    int pos = row_ptr[ea.cntoff[r] + dst] + rank[e];
    edge_src[pos] = ea.srcbase[r] + src;
}

__global__ void scan_bsum(const int* __restrict__ cnt, int n, int* __restrict__ bsums) {
    __shared__ int red[256];
    int i = blockIdx.x * 256 + threadIdx.x;
    red[threadIdx.x] = (i < n) ? cnt[i] : 0;
    __syncthreads();
    for (int s = 128; s; s >>= 1) {
        if (threadIdx.x < s) red[threadIdx.x] += red[threadIdx.x + s];
        __syncthreads();
    }
    if (threadIdx.x == 0) bsums[blockIdx.x] = red[0];
}

__global__ void scan_excl_single(int* __restrict__ data, int n) {
    __shared__ int buf[1024];
    __shared__ int carry_s;
    if (threadIdx.x == 0) carry_s = 0;
    __syncthreads();
    for (int base = 0; base < n; base += 1024) {
        int i = base + threadIdx.x;
        int v = (i < n) ? data[i] : 0;
        buf[threadIdx.x] = v;
        __syncthreads();
        for (int off = 1; off < 1024; off <<= 1) {
            int tv = (threadIdx.x >= off) ? buf[threadIdx.x - off] : 0;
            __syncthreads();
            buf[threadIdx.x] += tv;
            __syncthreads();
        }
        int incl = buf[threadIdx.x];
        int carry = carry_s;
        if (i < n) data[i] = carry + incl - v;
        __syncthreads();
        if (threadIdx.x == 1023) carry_s = carry + buf[1023];
        __syncthreads();
    }
}

__global__ void scan_rowptr(const int* __restrict__ cnt, const int* __restrict__ bsums,
                            int n, int* __restrict__ row_ptr) {
    __shared__ int buf[256];
    int i = blockIdx.x * 256 + threadIdx.x;
    int v = (i < n) ? cnt[i] : 0;
    buf[threadIdx.x] = v;
    __syncthreads();
    for (int off = 1; off < 256; off <<= 1) {
        int tv = (threadIdx.x >= off) ? buf[threadIdx.x - off] : 0;
        __syncthreads();
        buf[threadIdx.x] += tv;
        __syncthreads();
    }
    int excl = buf[threadIdx.x] - v + bsums[blockIdx.x];
    if (i < n) row_ptr[i] = excl;
    if (i == n - 1) row_ptr[n] = excl + v;
}

// ---------- gather-mean: half-wave (32 lanes) per dst row, unroll 16 ----------
__global__ void gather_mean(const __hip_bfloat16* __restrict__ x,
                            const int* __restrict__ edge_src,
                            const int* __restrict__ row_ptr,
                            __hip_bfloat16* __restrict__ agg, int nrows) {
    int w = blockIdx.x * 8 + (threadIdx.x >> 5);
    int lane = threadIdx.x & 31;
    if (w >= nrows) return;
    int s = row_ptr[w], t = row_ptr[w + 1];
    const unsigned* xu = (const unsigned*)x;
    float a0 = 0.f, a1 = 0.f;
    int e = s;
    for (; e + 16 <= t; e += 16) {
        unsigned v[16];
        #pragma unroll
        for (int u = 0; u < 16; ++u) v[u] = xu[(long)edge_src[e + u] * 32 + lane];
        #pragma unroll
        for (int u = 0; u < 16; ++u) { a0 += blo(v[u]); a1 += bhi(v[u]); }
    }
    for (; e + 4 <= t; e += 4) {
        unsigned v0 = xu[(long)edge_src[e] * 32 + lane];
        unsigned v1 = xu[(long)edge_src[e + 1] * 32 + lane];
        unsigned v2 = xu[(long)edge_src[e + 2] * 32 + lane];
        unsigned v3 = xu[(long)edge_src[e + 3] * 32 + lane];
        a0 += (blo(v0) + blo(v1)) + (blo(v2) + blo(v3));
        a1 += (bhi(v0) + bhi(v1)) + (bhi(v2) + bhi(v3));
    }
    for (; e < t; ++e) {
        unsigned v = xu[(long)edge_src[e] * 32 + lane];
        a0 += blo(v); a1 += bhi(v);
    }
    float inv = (t > s) ? 1.0f / (float)(t - s) : 0.f;
    __hip_bfloat162 o;
    o.x = __float2bfloat16(a0 * inv);
    o.y = __float2bfloat16(a1 * inv);
    ((__hip_bfloat162*)agg)[(long)w * 32 + lane] = o;
}

// ---------- layer update: register-resident weights, direct-global A, no LDS ----------
// x[d,:] = relu( sum_p agg_p[d,:] @ Wl_p + x[d,:] @ Wsum + blsum ),  in place.
struct UpdArgs {
    long aggOff[4][3];
    int wtSlot[4][4];
    long dstBase[4];
    int nDst[4];
    int Rdt[4];
    int blsumOff[4];
    int btBase[5];
    int totalBT;
};

__global__ __launch_bounds__(256) void update_layer(
    __hip_bfloat16* __restrict__ x,
    const __hip_bfloat16* __restrict__ agg,
    const bf16_t* __restrict__ wt,
    const float* __restrict__ blsum,
    UpdArgs ua, int btPerBlk) {
    int wv = threadIdx.x >> 6;
    int lane = threadIdx.x & 63;
    int quad = lane >> 4, l16 = lane & 15;
    int bt0 = blockIdx.x * btPerBlk;
    int bt1 = bt0 + btPerBlk;
    if (bt1 > ua.totalBT) bt1 = ua.totalBT;
    int curdt = -1;
    bf16x8 B[4][4][2];   // [pass][nt][kc] — compile-time indexed only

    for (int bt = bt0; bt < bt1; ++bt) {
        int slot = 0;
        while (slot < 3 && bt >= ua.btBase[slot + 1]) ++slot;
        int dt = slot;
        int R = ua.Rdt[dt];
        if (dt != curdt) {
            curdt = dt;
            #pragma unroll
            for (int p = 0; p < 4; ++p) {
                if (p <= R) {
                    const bf16_t* wb = wt + (long)ua.wtSlot[dt][p == R ? 3 : p] * 4096;
                    #pragma unroll
                    for (int nt = 0; nt < 4; ++nt)
                        #pragma unroll
                        for (int kc = 0; kc < 2; ++kc)
                            B[p][nt][kc] = *(const bf16x8*)(wb + (nt * 16 + l16) * 64 + kc * 32 + quad * 8);
                }
            }
        }
        long d0 = (long)(bt - ua.btBase[slot]) * 64 + wv * 16;
        f32x4 acc[4] = {};
        #pragma unroll
        for (int p = 0; p < 4; ++p) {
            if (p <= R) {
                const bf16_t* abase = (p == R)
                    ? (const bf16_t*)x + (ua.dstBase[dt] + d0) * 64
                    : (const bf16_t*)agg + (ua.aggOff[dt][p == R ? 0 : p] + d0) * 64;
                bf16x8 a0 = *(const bf16x8*)(abase + l16 * 64 + quad * 8);
                bf16x8 a1 = *(const bf16x8*)(abase + l16 * 64 + 32 + quad * 8);
                #pragma unroll
                for (int nt = 0; nt < 4; ++nt) {
                    acc[nt] = __builtin_amdgcn_mfma_f32_16x16x32_bf16(a0, B[p][nt][0], acc[nt], 0, 0, 0);
                    acc[nt] = __builtin_amdgcn_mfma_f32_16x16x32_bf16(a1, B[p][nt][1], acc[nt], 0, 0, 0);
                }
            }
        }
        const float* bs = blsum + ua.blsumOff[dt];
        int n_dst = ua.nDst[dt];
        #pragma unroll
        for (int nt = 0; nt < 4; ++nt) {
            int col = nt * 16 + l16;
            float bv = bs[col];
            #pragma unroll
            for (int reg = 0; reg < 4; ++reg) {
                long dd = d0 + quad * 4 + reg;
                if (dd < n_dst)
                    x[(ua.dstBase[dt] + dd) * 64 + col] =
                        __float2bfloat16(fmaxf(acc[nt][reg] + bv, 0.f));
            }
        }
    }
}

// ---------- head: softplus(x@projW+projb) @ outW + outb ----------
__global__ __launch_bounds__(256) void head_k(
    const __hip_bfloat16* __restrict__ xc,
    const void* __restrict__ projW, const void* __restrict__ projb,
    const void* __restrict__ outW, const void* __restrict__ outb,
    void* __restrict__ out, const unsigned int* __restrict__ flags, int n) {
    __shared__ float PW[64 * 64];
    __shared__ float PB[64], OW[64];
    __shared__ float ROW[4][64];
    bool wf32 = flags[2] > 64;
    bool of32 = flags[1] > 64;
    int t = threadIdx.x;
    for (int i = t; i < 4096; i += 256) PW[i] = wload(projW, i, wf32);
    if (t < 64) { PB[t] = wload(projb, t, wf32); OW[t] = wload(outW, t, wf32); }
    int wid = t >> 6, lane = t & 63;
    int d = blockIdx.x * 4 + wid;
    ROW[wid][lane] = (d < n) ? __bfloat162float(xc[(long)d * H64 + lane]) : 0.f;
    __syncthreads();
    if (d < n) {
        float s = PB[lane];
        #pragma unroll 8
        for (int k = 0; k < 64; ++k) s += ROW[wid][k] * PW[k * 64 + lane];
        float sp = fmaxf(s, 0.f) + log1pf(expf(-fabsf(s)));
        float c = sp * OW[lane];
        #pragma unroll
        for (int off = 32; off; off >>= 1) c += __shfl_down(c, off, 64);
        if (lane == 0) {
            float rv = c + wload(outb, 0, wf32);
            if (of32) ((float*)out)[d] = rv;
            else ((__hip_bfloat16*)out)[d] = __float2bfloat16(rv);
        }
    }
}

extern "C" void kernel_launch(void* const* d_in, const int* in_sizes, int n_in,
                              void* d_out, int out_size, void* d_ws, size_t ws_size,
                              hipStream_t stream) {
    static const int rel_st[9] = {0, 0, 0, 1, 1, 2, 0, 1, 2};
    static const int rel_dt[9] = {0, 1, 2, 1, 2, 2, 3, 3, 3};
    static const int relsOf[4][3] = {{0, -1, -1}, {1, 3, -1}, {2, 4, 5}, {6, 7, 8}};
    static const int Rof[4] = {1, 2, 3, 3};

    long rows[4], rowoff[4], total = 0;
    for (int t = 0; t < 4; ++t) { rows[t] = in_sizes[t] / H64; rowoff[t] = total; total += rows[t]; }
    long NX = total * H64;
    long Es[9], ET = 0;
    for (int r = 0; r < 9; ++r) { Es[r] = (long)in_sizes[11 + r] / 2; ET += Es[r]; }
    long cntoff[9], cntN = 0;
    for (int r = 0; r < 9; ++r) { cntoff[r] = cntN; cntN += rows[rel_dt[r]]; }
    long nb1 = (cntN + 255) / 256;

    unsigned int* flags = (unsigned int*)d_ws;
    char* wsbase = (char*)d_ws + 64;
    auto align16 = [](size_t v) { return (v + 15) & ~(size_t)15; };
    size_t off = 0;
    __hip_bfloat16* x = (__hip_bfloat16*)(wsbase + off);   off = align16(off + (size_t)NX * 2);
    __hip_bfloat16* agg = (__hip_bfloat16*)(wsbase + off); off = align16(off + (size_t)cntN * H64 * 2);
    int* cnt_i = (int*)(wsbase + off);                     off = align16(off + (size_t)cntN * 4);
    int* row_ptr = (int*)(wsbase + off);                   off = align16(off + (size_t)(cntN + 1) * 4);
    int* rank = (int*)(wsbase + off);                      off = align16(off + (size_t)ET * 4);
    int* edge_src = (int*)(wsbase + off);                  off = align16(off + (size_t)ET * 4);
    int* bsums = (int*)(wsbase + off);                     off = align16(off + (size_t)nb1 * 4);
    bf16_t* wt = (bf16_t*)(wsbase + off);                  off = align16(off + (size_t)39 * 4096 * 2);
    float* blsum = (float*)(wsbase + off);                 off = align16(off + (size_t)12 * 64 * 4);

    // format detection
    hipMemsetAsync(d_ws, 0, 64, stream);
    int nwords = 16384;
    if (in_sizes[11] < nwords) nwords = in_sizes[11];
    detect_k<<<1, 256, 0, stream>>>((const unsigned int*)d_in[11], nwords,
                                    (const unsigned short*)d_in[0],
                                    (const unsigned short*)d_in[4], flags);

    // x inputs -> bf16 ws (single dispatch)
    ConvArgs ca;
    for (int t = 0; t < 4; ++t) { ca.src[t] = d_in[t]; ca.elemoff[t] = rowoff[t] * H64; }
    ca.elemoff[4] = NX;
    {
        int blocks = (int)((NX + 255) / 256); if (blocks > 8192) blocks = 8192;
        conv_in_all<<<blocks, 256, 0, stream>>>(ca, x, flags);
    }

    // weight prep (transpose + pre-sum, bf16)
    prep_w<<<39, 256, 0, stream>>>(d_in[4], d_in[6], d_in[5], flags, wt, blsum);

    // CSR build (edge structure is layer-invariant)
    EdgeArgs ea;
    long ecum = 0;
    for (int r = 0; r < 9; ++r) {
        ea.ei[r] = (const int*)d_in[11 + r];
        ea.eoff[r] = ecum; ecum += Es[r];
        ea.cntoff[r] = (int)cntoff[r];
        ea.srcbase[r] = (int)rowoff[rel_st[r]];
    }
    ea.eoff[9] = ecum;

    hipMemsetAsync(cnt_i, 0, (size_t)cntN * 4, stream);
    count_all<<<(int)((ET + 255) / 256), 256, 0, stream>>>(ea, flags, cnt_i, rank);
    scan_bsum<<<(int)nb1, 256, 0, stream>>>(cnt_i, (int)cntN, bsums);
    scan_excl_single<<<1, 1024, 0, stream>>>(bsums, (int)nb1);
    scan_rowptr<<<(int)nb1, 256, 0, stream>>>(cnt_i, bsums, (int)cntN, row_ptr);
    fill_all<<<(int)((ET + 255) / 256), 256, 0, stream>>>(ea, flags, row_ptr, rank, edge_src);

    // update-layer argument block (layer-invariant parts)
    UpdArgs ua;
    int bb = 0;
    for (int dt = 0; dt < 4; ++dt) {
        ua.nDst[dt] = (int)rows[dt];
        ua.Rdt[dt] = Rof[dt];
        ua.dstBase[dt] = rowoff[dt];
        ua.btBase[dt] = bb;
        bb += (int)((rows[dt] + 63) / 64);
        for (int p = 0; p < 3; ++p) {
            int rr = (p < Rof[dt]) ? relsOf[dt][p] : relsOf[dt][0];
            ua.aggOff[dt][p] = cntoff[rr];
        }
    }
    ua.btBase[4] = bb;
    ua.totalBT = bb;
    int btPerBlk = (bb + 1023) / 1024;
    if (btPerBlk < 1) btPerBlk = 1;
    int updGrid = (bb + btPerBlk - 1) / btPerBlk;

    // layers: gather (x -> agg), then in-place MFMA update
    for (int l = 0; l < 3; ++l) {
        gather_mean<<<(int)((cntN + 7) / 8), 256, 0, stream>>>(
            x, edge_src, row_ptr, agg, (int)cntN);
        for (int dt = 0; dt < 4; ++dt) {
            ua.blsumOff[dt] = (l * 4 + dt) * 64;
            for (int p = 0; p < 3; ++p) {
                int rr = (p < Rof[dt]) ? relsOf[dt][p] : relsOf[dt][0];
                ua.wtSlot[dt][p] = l * 13 + rr;
            }
            ua.wtSlot[dt][3] = l * 13 + 9 + dt;
        }
        update_layer<<<updGrid, 256, 0, stream>>>(x, agg, wt, blsum, ua, btPerBlk);
    }

    head_k<<<(int)((rows[3] + 3) / 4), 256, 0, stream>>>(
        x + rowoff[3] * H64, d_in[7], d_in[8], d_in[9], d_in[10], d_out, flags, (int)rows[3]);
}